// Round 1
// baseline (273.690 us; speedup 1.0000x reference)
//
#include <hip/hip_runtime.h>
#include <hip/hip_bf16.h>

// Problem constants
#define NB     32
#define CIN    256
#define LIN    4096
#define COUT   256
#define KW     9
#define NGRP   4
#define CDIM   128
#define CPG    64          // channels per group (both in and out)
#define LT     256         // l-tile per workgroup
#define LROWS  264         // LT + KW - 1
#define RSTR   72          // padded LDS row stride (elements); 144 B, 16B-aligned
#define WF_ELEMS (4*4*9*2*64*8)   // g * co16 * k * chunk * lane * j = 294912

typedef __attribute__((ext_vector_type(8))) short short8;   // 8 bf16 = 4 VGPRs
typedef __attribute__((ext_vector_type(4))) float float4v;  // 4 fp32

// ---- Pack weights (fp32, [co][ci][k]) into MFMA A-fragment-linear bf16 order ----
// wF[((((g*4+co16)*9+k)*2+chunk)*64+lane)*8 + j] = w[co= g*64+co16*16+(lane&15)][ci= chunk*32+(lane>>4)*8+j][k]
__global__ void pack_weights(const float* __restrict__ w, __hip_bfloat16* __restrict__ wF) {
    int tid = blockIdx.x * blockDim.x + threadIdx.x;
    if (tid >= WF_ELEMS) return;
    int j    = tid & 7;
    int lane = (tid >> 3) & 63;
    int rest = tid >> 9;
    int chunk = rest & 1;  rest >>= 1;
    int k     = rest % 9;  rest /= 9;
    int co16  = rest & 3;
    int g     = rest >> 2;
    int co = g * CPG + co16 * 16 + (lane & 15);
    int ci = chunk * 32 + (lane >> 4) * 8 + j;
    wF[tid] = __float2bfloat16(w[(co * CPG + ci) * KW + k]);
}

// ---- ctx[n][co] = c[n] . c_weight[co] + bias[co] ----
__global__ void ctx_kernel(const float* __restrict__ c, const float* __restrict__ cw,
                           const float* __restrict__ bias, float* __restrict__ ctxb) {
    int tid = blockIdx.x * blockDim.x + threadIdx.x;   // [0, 32*256)
    int n  = tid >> 8;
    int co = tid & 255;
    const float* cp = c  + n  * CDIM;
    const float* wp = cw + co * CDIM;
    float s = bias[co];
    #pragma unroll 4
    for (int d = 0; d < CDIM; ++d) s += cp[d] * wp[d];
    ctxb[tid] = s;
}

// ---- Main: implicit-GEMM grouped conv via bf16 MFMA ----
__global__ __launch_bounds__(256) void conv_mfma(
    const float* __restrict__ x, const __hip_bfloat16* __restrict__ wF,
    const float* __restrict__ ctxb, float* __restrict__ out)
{
    __shared__ __hip_bfloat16 xT[LROWS * RSTR];  // transposed x tile: [l_local][ci], 38,016 B
    __shared__ float sctx[CPG];

    const int bx = blockIdx.x;          // 2048 blocks = n(32) * g(4) * tile(16)
    const int t  = bx & 15;
    const int g  = (bx >> 4) & 3;
    const int n  = bx >> 6;
    const int l0 = t * LT;
    const int tid = threadIdx.x;

    if (tid < CPG) sctx[tid] = ctxb[n * COUT + g * CPG + tid];

    // Stage x tile, transposed to [l][ci], fp32 -> bf16.
    // Lanes sweep ci at fixed l4: global reads = float4/lane fully coalesced per row-quad,
    // LDS writes: 64 lanes hit one row, 2 lanes per dword -> conflict-free.
    const float* xb = x + ((long)(n * CIN + g * CPG)) * LIN;
    for (int it = 0; it < 17; ++it) {
        int idx = it * 256 + tid;                 // 66 l4-chunks * 64 ci = 4224
        if (idx < 66 * 64) {
            int ci = idx & 63;
            int l4 = idx >> 6;
            int lg = l0 - 4 + 4 * l4;             // aligned; fully in or fully out of [0,LIN)
            float4v v = {0.f, 0.f, 0.f, 0.f};
            if (lg >= 0 && lg < LIN)
                v = *(const float4v*)(xb + (long)ci * LIN + lg);
            int lb = 4 * l4;
            xT[(lb + 0) * RSTR + ci] = __float2bfloat16(v[0]);
            xT[(lb + 1) * RSTR + ci] = __float2bfloat16(v[1]);
            xT[(lb + 2) * RSTR + ci] = __float2bfloat16(v[2]);
            xT[(lb + 3) * RSTR + ci] = __float2bfloat16(v[3]);
        }
    }
    __syncthreads();

    const int lane = tid & 63;
    const int wv   = tid >> 6;      // wave id: l sub-tile
    const int r    = lane & 15;
    const int q    = lane >> 4;
    const int wl   = wv * 64;

    float4v acc[4][4];              // [co16][l16]
    #pragma unroll
    for (int a = 0; a < 4; ++a)
        #pragma unroll
        for (int b = 0; b < 4; ++b)
            acc[a][b] = (float4v){0.f, 0.f, 0.f, 0.f};

    const short8* wFp = (const short8*)wF;

    #pragma unroll
    for (int k = 0; k < KW; ++k) {
        #pragma unroll
        for (int chunk = 0; chunk < 2; ++chunk) {
            short8 bfrag[4];
            #pragma unroll
            for (int l16 = 0; l16 < 4; ++l16) {
                int row = wl + l16 * 16 + r + k;            // out-l + k shift
                bfrag[l16] = *(const short8*)(&xT[row * RSTR + chunk * 32 + q * 8]);
            }
            short8 afrag[4];
            #pragma unroll
            for (int co16 = 0; co16 < 4; ++co16) {
                afrag[co16] = wFp[(((g * 4 + co16) * 9 + k) * 2 + chunk) * 64 + lane];
            }
            #pragma unroll
            for (int co16 = 0; co16 < 4; ++co16)
                #pragma unroll
                for (int l16 = 0; l16 < 4; ++l16)
                    acc[co16][l16] = __builtin_amdgcn_mfma_f32_16x16x32_bf16(
                        afrag[co16], bfrag[l16], acc[co16][l16], 0, 0, 0);
        }
    }

    // Epilogue: D layout col = lane&15 (l), row = q*4+reg (co). Add ctx+bias, store coalesced.
    float* ob = out + ((long)(n * COUT + g * CPG)) * LIN + l0 + wl;
    #pragma unroll
    for (int co16 = 0; co16 < 4; ++co16) {
        #pragma unroll
        for (int reg = 0; reg < 4; ++reg) {
            int co_l = co16 * 16 + q * 4 + reg;
            float add = sctx[co_l];
            #pragma unroll
            for (int l16 = 0; l16 < 4; ++l16) {
                ob[(long)co_l * LIN + l16 * 16 + r] = acc[co16][l16][reg] + add;
            }
        }
    }
}

extern "C" void kernel_launch(void* const* d_in, const int* in_sizes, int n_in,
                              void* d_out, int out_size, void* d_ws, size_t ws_size,
                              hipStream_t stream) {
    const float* x   = (const float*)d_in[0];   // (32, 256, 4096)
    const float* c   = (const float*)d_in[1];   // (32, 128)
    const float* w   = (const float*)d_in[2];   // (256, 64, 9)
    const float* cw  = (const float*)d_in[3];   // (256, 128)
    const float* bias= (const float*)d_in[4];   // (256,)
    float* out = (float*)d_out;                 // (32, 256, 4096)

    __hip_bfloat16* wF = (__hip_bfloat16*)d_ws;                       // 589,824 B
    float* ctxb = (float*)((char*)d_ws + (size_t)WF_ELEMS * 2);       // 32,768 B

    pack_weights<<<(WF_ELEMS + 255) / 256, 256, 0, stream>>>(w, wF);
    ctx_kernel<<<(NB * COUT) / 256, 256, 0, stream>>>(c, cw, bias, ctxb);
    conv_mfma<<<NB * NGRP * (LIN / LT), 256, 0, stream>>>(x, wF, ctxb, out);
}

// Round 2
// 259.880 us; speedup vs baseline: 1.0531x; 1.0531x over previous
//
#include <hip/hip_runtime.h>
#include <hip/hip_bf16.h>

// Problem constants
#define NB     32
#define CIN    256
#define LIN    4096
#define COUT   256
#define KW     9
#define NGRP   4
#define CDIM   128
#define CPG    64          // channels per group (both in and out)
#define LT     256         // l-tile per workgroup
#define NROWS  264         // LT + 2*PAD halo rows
#define RP     68          // LDS row stride in bf16 elements: 136 B (8B-aligned b64, odd*34 dwords spreads banks)
#define WF_ELEMS (4*4*9*2*64*8)   // g * co16 * k * chunk * lane * j = 294912

typedef __attribute__((ext_vector_type(8))) short short8;    // 8 bf16 = 4 VGPRs (MFMA operand)
typedef __attribute__((ext_vector_type(4))) short short4v;
typedef __attribute__((ext_vector_type(4))) float float4v;
typedef __attribute__((ext_vector_type(4))) unsigned short ushort4v;

// ---- Pack weights (fp32, [co][ci][k]) into MFMA A-fragment-linear bf16 order ----
// wF[((((g*4+co16)*9+k)*2+chunk)*64+lane)*8 + j] = w[co= g*64+co16*16+(lane&15)][ci= chunk*32+(lane>>4)*8+j][k]
__global__ void pack_weights(const float* __restrict__ w, __hip_bfloat16* __restrict__ wF) {
    int tid = blockIdx.x * blockDim.x + threadIdx.x;
    if (tid >= WF_ELEMS) return;
    int j    = tid & 7;
    int lane = (tid >> 3) & 63;
    int rest = tid >> 9;
    int chunk = rest & 1;  rest >>= 1;
    int k     = rest % 9;  rest /= 9;
    int co16  = rest & 3;
    int g     = rest >> 2;
    int co = g * CPG + co16 * 16 + (lane & 15);
    int ci = chunk * 32 + (lane >> 4) * 8 + j;
    wF[tid] = __float2bfloat16(w[(co * CPG + ci) * KW + k]);
}

// ---- ctx[n][co] = c[n] . c_weight[co] + bias[co] : one wave per output, coalesced ----
__global__ __launch_bounds__(256) void ctx_kernel(const float* __restrict__ c,
                                                  const float* __restrict__ cw,
                                                  const float* __restrict__ bias,
                                                  float* __restrict__ ctxb) {
    int gw   = (blockIdx.x * 256 + threadIdx.x) >> 6;   // wave id: [0, 32*256)
    int lane = threadIdx.x & 63;
    int n  = gw >> 8;
    int co = gw & 255;
    float s = c[n * CDIM + lane]      * cw[co * CDIM + lane]
            + c[n * CDIM + 64 + lane] * cw[co * CDIM + 64 + lane];
    #pragma unroll
    for (int off = 32; off; off >>= 1) s += __shfl_down(s, off);
    if (lane == 0) ctxb[gw] = s + bias[co];
}

// ---- Main: implicit-GEMM grouped conv via bf16 MFMA ----
// Staging: coalesced float4 reads (lanes sweep l), in-register 4x4 transpose,
// b64 LDS writes into [l][ci] rows (RP=68).
__global__ __launch_bounds__(256, 4) void conv_mfma(
    const float* __restrict__ x, const __hip_bfloat16* __restrict__ wF,
    const float* __restrict__ ctxb, float* __restrict__ out)
{
    __shared__ unsigned short sx[NROWS * RP];   // [row][ci], row = l_local (l = l0-4+row), 35,904 B
    __shared__ float sctx[CPG];

    const int bx = blockIdx.x;          // 2048 blocks = n(32) * g(4) * tile(16)
    const int t  = bx & 15;
    const int g  = (bx >> 4) & 3;
    const int n  = bx >> 6;
    const int l0 = t * LT;
    const int tid = threadIdx.x;
    const int lane = tid & 63;
    const int wv   = tid >> 6;

    if (tid < CPG) sctx[tid] = ctxb[n * COUT + g * CPG + tid];

    const float* xb = x + ((size_t)(n * CIN + g * CPG)) * LIN;

    // ---- Main staging: q4 (l-quad) = 1..64 -> rows 4..259, always in-bounds ----
    // Per wave-instr: 16 lanes sweep q4 (256B contiguous) x 4 ci rows -> coalesced.
    {
        int q4  = 1 + (lane & 15);
        int cqb = 4 * wv + (lane >> 4);   // ci-quad 0..15
        #pragma unroll
        for (int i = 0; i < 4; ++i, q4 += 16) {
            int lg = l0 - 4 + 4 * q4;
            float4v v[4];
            #pragma unroll
            for (int j = 0; j < 4; ++j)
                v[j] = *(const float4v*)(xb + (size_t)(4 * cqb + j) * LIN + lg);
            int row = 4 * q4;
            #pragma unroll
            for (int d = 0; d < 4; ++d) {
                ushort4v p;
                #pragma unroll
                for (int j = 0; j < 4; ++j)
                    p[j] = __builtin_bit_cast(unsigned short, __float2bfloat16(v[j][d]));
                *(ushort4v*)(&sx[(row + d) * RP + 4 * cqb]) = p;
            }
        }
    }
    // ---- Halo rows 0..3 (l0-4..l0-1) and 260..263 (l0+256..l0+259), block-uniform validity ----
    if (tid < 32) {
        int head = (tid < 16);
        int q4 = head ? 0 : 65;
        int cq = tid & 15;
        int lg = l0 - 4 + 4 * q4;
        bool ok = head ? (t > 0) : (t < 15);
        float4v v[4];
        #pragma unroll
        for (int j = 0; j < 4; ++j)
            v[j] = ok ? *(const float4v*)(xb + (size_t)(4 * cq + j) * LIN + lg)
                      : (float4v){0.f, 0.f, 0.f, 0.f};
        int row = 4 * q4;                 // 0 or 260
        #pragma unroll
        for (int d = 0; d < 4; ++d) {
            ushort4v p;
            #pragma unroll
            for (int j = 0; j < 4; ++j)
                p[j] = __builtin_bit_cast(unsigned short, __float2bfloat16(v[j][d]));
            *(ushort4v*)(&sx[(row + d) * RP + 4 * cq]) = p;
        }
    }
    __syncthreads();

    const int r  = lane & 15;
    const int q  = lane >> 4;
    const int wl = wv * 64;

    float4v acc[4][4];              // [co16][l16]
    #pragma unroll
    for (int a = 0; a < 4; ++a)
        #pragma unroll
        for (int b = 0; b < 4; ++b)
            acc[a][b] = (float4v){0.f, 0.f, 0.f, 0.f};

    const short8* wFp = (const short8*)wF;

    #pragma unroll
    for (int k = 0; k < KW; ++k) {
        #pragma unroll
        for (int chunk = 0; chunk < 2; ++chunk) {
            short8 bfrag[4];
            #pragma unroll
            for (int l16 = 0; l16 < 4; ++l16) {
                int row = wl + l16 * 16 + r + k;            // out-l + k shift
                int base = row * RP + chunk * 32 + q * 8;
                short4v lo = *(const short4v*)(&sx[base]);
                short4v hi = *(const short4v*)(&sx[base + 4]);
                bfrag[l16] = __builtin_shufflevector(lo, hi, 0, 1, 2, 3, 4, 5, 6, 7);
            }
            short8 afrag[4];
            #pragma unroll
            for (int co16 = 0; co16 < 4; ++co16) {
                afrag[co16] = wFp[(((g * 4 + co16) * 9 + k) * 2 + chunk) * 64 + lane];
            }
            #pragma unroll
            for (int co16 = 0; co16 < 4; ++co16)
                #pragma unroll
                for (int l16 = 0; l16 < 4; ++l16)
                    acc[co16][l16] = __builtin_amdgcn_mfma_f32_16x16x32_bf16(
                        afrag[co16], bfrag[l16], acc[co16][l16], 0, 0, 0);
        }
    }

    // Epilogue: D layout col = lane&15 (l), row = q*4+reg (co). Add ctx+bias, store coalesced.
    float* ob = out + ((size_t)(n * COUT + g * CPG)) * LIN + l0 + wl;
    #pragma unroll
    for (int co16 = 0; co16 < 4; ++co16) {
        #pragma unroll
        for (int reg = 0; reg < 4; ++reg) {
            int co_l = co16 * 16 + q * 4 + reg;
            float add = sctx[co_l];
            #pragma unroll
            for (int l16 = 0; l16 < 4; ++l16) {
                ob[(size_t)co_l * LIN + l16 * 16 + r] = acc[co16][l16][reg] + add;
            }
        }
    }
}

extern "C" void kernel_launch(void* const* d_in, const int* in_sizes, int n_in,
                              void* d_out, int out_size, void* d_ws, size_t ws_size,
                              hipStream_t stream) {
    const float* x    = (const float*)d_in[0];   // (32, 256, 4096)
    const float* c    = (const float*)d_in[1];   // (32, 128)
    const float* w    = (const float*)d_in[2];   // (256, 64, 9)
    const float* cw   = (const float*)d_in[3];   // (256, 128)
    const float* bias = (const float*)d_in[4];   // (256,)
    float* out = (float*)d_out;                  // (32, 256, 4096)

    __hip_bfloat16* wF = (__hip_bfloat16*)d_ws;                       // 589,824 B
    float* ctxb = (float*)((char*)d_ws + (size_t)WF_ELEMS * 2);       // 32,768 B

    pack_weights<<<(WF_ELEMS + 255) / 256, 256, 0, stream>>>(w, wF);
    ctx_kernel<<<(NB * COUT * 64) / 256, 256, 0, stream>>>(c, cw, bias, ctxb);
    conv_mfma<<<NB * NGRP * (LIN / LT), 256, 0, stream>>>(x, wF, ctxb, out);
}